// Round 6
// baseline (164.482 us; speedup 1.0000x reference)
//
#include <hip/hip_runtime.h>

// x: (B=4, C=64, H=512, W=512) fp32 -> 131072 independent rows of 512 cols.
// FIR (5-tap SAME) then IIR y[j] = f[j] - (v0*y[j-3] + v1*y[j-2] + v2*y[j-1]).
//
// Segment-parallel (linearity): thread = (row, 32-col segment), 8x16 = 128/block.
// This round: A/B diagnostic for the exact-2x WRITE_SIZE anomaly.
//   Variant A drain: R1-shaped stores (two 128B segments @ 2KB stride / instr)
//   Variant B drain: contiguous 256B/instr stores (R5 control)
// Two dispatches, half the rows each; everything else identical.

constexpr int Wd     = 512;
constexpr int TROWS  = 8;
constexpr int NT     = 128;
constexpr int SEGS   = 16;
constexpr int SEGP4  = 9;                  // float4 pitch per segment (8 data + 1 pad)
constexpr int ROWP4  = SEGS * SEGP4;       // 144 float4 per row
constexpr int F4ROW  = Wd / 4;             // 128
constexpr int ROWF   = ROWP4 * 4;          // 576 floats LDS row pitch
constexpr int SEGF   = SEGP4 * 4;          // 36 floats LDS segment pitch

template<int VAR>
__global__ __launch_bounds__(NT, 4)
void iir_conv2d_kernel(const float4* __restrict__ x4,
                       const float* __restrict__ w1,   // (C,1,5)
                       const float* __restrict__ w2,   // (C,3)
                       float4* __restrict__ y4,
                       int blk0)
{
    __shared__ float4 tile[TROWS * ROWP4];   // 18432 B; x then y in place
    __shared__ float  Htab[32][3];           // homogeneous responses
    __shared__ float  TP[3][3][3];           // T^2, T^4, T^8

    const int tid  = threadIdx.x;
    const int lane = tid & 63;
    const int row0 = (blockIdx.x + blk0) * TROWS;  // 8 | 512 -> channel uniform
    const int c    = (row0 >> 9) & 63;

    // ---- issue coalesced global loads first ----
    const float4* __restrict__ xb = x4 + (size_t)row0 * F4ROW;
    float4 st[8];
    #pragma unroll
    for (int it = 0; it < 8; ++it) st[it] = xb[it * NT + tid];

    const float v0 = w2[c*3+0], v1 = w2[c*3+1], v2 = w2[c*3+2];

    // ---- Htab + T powers (thread 0; hidden under load latency) ----
    if (tid == 0) {
        float h3[3] = {1.f, 0.f, 0.f};
        float h2[3] = {0.f, 1.f, 0.f};
        float h1[3] = {0.f, 0.f, 1.f};
        for (int k = 0; k < 32; ++k) {
            #pragma unroll
            for (int j = 0; j < 3; ++j) {
                const float n = -(v0*h3[j] + v1*h2[j] + v2*h1[j]);
                Htab[k][j] = n;
                h3[j] = h2[j]; h2[j] = h1[j]; h1[j] = n;
            }
        }
        float T1[3][3], T2[3][3], T4[3][3];
        #pragma unroll
        for (int i = 0; i < 3; ++i)
            #pragma unroll
            for (int j = 0; j < 3; ++j) T1[i][j] = Htab[29+i][j];
        #pragma unroll
        for (int i = 0; i < 3; ++i)
            #pragma unroll
            for (int j = 0; j < 3; ++j) {
                float acc = 0.f;
                #pragma unroll
                for (int k = 0; k < 3; ++k) acc += T1[i][k]*T1[k][j];
                T2[i][j] = acc; TP[0][i][j] = acc;
            }
        #pragma unroll
        for (int i = 0; i < 3; ++i)
            #pragma unroll
            for (int j = 0; j < 3; ++j) {
                float acc = 0.f;
                #pragma unroll
                for (int k = 0; k < 3; ++k) acc += T2[i][k]*T2[k][j];
                T4[i][j] = acc; TP[1][i][j] = acc;
            }
        #pragma unroll
        for (int i = 0; i < 3; ++i)
            #pragma unroll
            for (int j = 0; j < 3; ++j) {
                float acc = 0.f;
                #pragma unroll
                for (int k = 0; k < 3; ++k) acc += T4[i][k]*T4[k][j];
                TP[2][i][j] = acc;
            }
    }

    // ---- stage x into LDS ----
    #pragma unroll
    for (int it = 0; it < 8; ++it) {
        const int idx = it * NT + tid;
        const int r = idx >> 7, g = idx & 127;
        tile[r * ROWP4 + (g >> 3) * SEGP4 + (g & 7)] = st[it];
    }
    __syncthreads();

    // ---- phase 1: particular solution per segment ----
    const int r = tid >> 4;        // row in tile
    const int s = tid & 15;        // segment
    const float a0 = w1[c*5+0], a1 = w1[c*5+1], a2 = w1[c*5+2],
                a3 = w1[c*5+3], a4 = w1[c*5+4];

    float xfl[40];                 // cols j0-4 .. j0+35
    #pragma unroll
    for (int k = 0; k < 10; ++k) {
        const int g = s * 8 + k - 1;
        const bool valid = (g >= 0) && (g < F4ROW);
        const int gg = valid ? g : 0;
        float4 v = tile[r * ROWP4 + (gg >> 3) * SEGP4 + (gg & 7)];
        if (!valid) { v.x = 0.f; v.y = 0.f; v.z = 0.f; v.w = 0.f; }
        xfl[4*k+0] = v.x; xfl[4*k+1] = v.y; xfl[4*k+2] = v.z; xfl[4*k+3] = v.w;
    }
    float y[32];
    {
        float ym3 = 0.f, ym2 = 0.f, ym1 = 0.f;
        #pragma unroll
        for (int k = 0; k < 32; ++k) {
            const float f = a0*xfl[k+2] + a1*xfl[k+3] + a2*xfl[k+4]
                          + a3*xfl[k+5] + a4*xfl[k+6];
            const float t = v0*ym3 + v1*ym2;      // off the serial chain
            const float yy = (f - t) - v2*ym1;
            y[k] = yy;
            ym3 = ym2; ym2 = ym1; ym1 = yy;
        }
    }

    // ---- affine scan over segments (in-wave, shuffles only) ----
    float b0 = y[29], b1 = y[30], b2 = y[31];
    #pragma unroll
    for (int rd = 0; rd < 4; ++rd) {
        const int d = 1 << rd;
        float t00, t01, t02, t10, t11, t12, t20, t21, t22;
        if (rd == 0) {
            t00 = Htab[29][0]; t01 = Htab[29][1]; t02 = Htab[29][2];
            t10 = Htab[30][0]; t11 = Htab[30][1]; t12 = Htab[30][2];
            t20 = Htab[31][0]; t21 = Htab[31][1]; t22 = Htab[31][2];
        } else {
            t00 = TP[rd-1][0][0]; t01 = TP[rd-1][0][1]; t02 = TP[rd-1][0][2];
            t10 = TP[rd-1][1][0]; t11 = TP[rd-1][1][1]; t12 = TP[rd-1][1][2];
            t20 = TP[rd-1][2][0]; t21 = TP[rd-1][2][1]; t22 = TP[rd-1][2][2];
        }
        const int src = (s >= d) ? (lane - d) : lane;
        const float g0 = __shfl(b0, src, 64);
        const float g1 = __shfl(b1, src, 64);
        const float g2 = __shfl(b2, src, 64);
        if (s >= d) {
            b0 += t00*g0 + t01*g1 + t02*g2;
            b1 += t10*g0 + t11*g1 + t12*g2;
            b2 += t20*g0 + t21*g1 + t22*g2;
        }
    }
    {
        const int src = (s >= 1) ? (lane - 1) : lane;
        float s0 = __shfl(b0, src, 64);
        float s1 = __shfl(b1, src, 64);
        float s2 = __shfl(b2, src, 64);
        if (s == 0) { s0 = 0.f; s1 = 0.f; s2 = 0.f; }
        #pragma unroll
        for (int k = 0; k < 32; ++k)
            y[k] += Htab[k][0]*s0 + Htab[k][1]*s1 + Htab[k][2]*s2;
    }
    __syncthreads();   // all tile reads (phase 1) complete before overwrite

    // ---- write y into tile (in place) ----
    #pragma unroll
    for (int u = 0; u < 8; ++u) {
        float4 o;
        o.x = y[4*u+0]; o.y = y[4*u+1]; o.z = y[4*u+2]; o.w = y[4*u+3];
        tile[r * ROWP4 + s * SEGP4 + u] = o;
    }
    __syncthreads();

    // ---- drain ----
    const float* __restrict__ tf = reinterpret_cast<const float*>(tile);
    float* __restrict__ yb = reinterpret_cast<float*>(y4 + (size_t)row0 * F4ROW);

    if (VAR == 0) {
        // A: R1-shaped — per instruction, lanes cover 2 rows x 32 cols
        //    = two 128B segments at 2KB stride.
        #pragma unroll
        for (int it = 0; it < 32; ++it) {
            const int e     = it * NT + tid;
            const int chunk = e >> 8;          // 0..15
            const int rr    = (e >> 5) & 7;    // row in tile
            const int col   = e & 31;
            yb[rr * Wd + chunk * 32 + col] = tf[rr * ROWF + chunk * SEGF + col];
        }
    } else {
        // B: contiguous 256B per wave instruction (R5 control).
        #pragma unroll
        for (int it = 0; it < 32; ++it) {
            const int idx = it * NT + tid;
            const int rr  = idx >> 9;
            const int g   = idx & 511;
            yb[idx] = tf[rr * ROWF + (g >> 5) * SEGF + (g & 31)];
        }
    }
}

extern "C" void kernel_launch(void* const* d_in, const int* in_sizes, int n_in,
                              void* d_out, int out_size, void* d_ws, size_t ws_size,
                              hipStream_t stream) {
    const float4* x4 = (const float4*)d_in[0];
    const float*  w1 = (const float*)d_in[1];
    const float*  w2 = (const float*)d_in[2];
    float4* y4 = (float4*)d_out;

    const int nrows  = out_size / Wd;        // 131072
    const int blocks = nrows / TROWS;        // 16384
    const int half   = blocks / 2;           // 8192

    iir_conv2d_kernel<0><<<half, NT, 0, stream>>>(x4, w1, w2, y4, 0);
    iir_conv2d_kernel<1><<<half, NT, 0, stream>>>(x4, w1, w2, y4, half);
}

// Round 8
// 152.422 us; speedup vs baseline: 1.0791x; 1.0791x over previous
//
#include <hip/hip_runtime.h>

// x: (B=4, C=64, H=512, W=512) fp32 -> 131072 independent rows of 512 cols.
// FIR (5-tap SAME) then IIR y[j] = f[j] - (v0*y[j-3] + v1*y[j-2] + v2*y[j-1]).
//
// Segment-parallel (linearity): thread = (row, 32-col segment), 8x16 = 128/block.
//   phase1: per-segment particular solution (zero entry state), serial 32
//   scan  : in-wave Hillis-Steele affine scan over segments (shuffles)
//   fixup : y[k] += Htab[k] . s_enter
// R8 = R7 intent, compile-fixed: NON-TEMPORAL drain stores via native
// ext_vector_type(4) (HIP float4 is rejected by the builtin). Contiguous
// 1KB per wave instruction; bypasses suspected L2 write-allocate (2x WRITE).

constexpr int Wd     = 512;
constexpr int TROWS  = 8;
constexpr int NT     = 128;
constexpr int SEGS   = 16;
constexpr int SEGP4  = 9;                  // float4 pitch per segment (8 data + 1 pad)
constexpr int ROWP4  = SEGS * SEGP4;       // 144 float4 per row
constexpr int F4ROW  = Wd / 4;             // 128

typedef float floatx4 __attribute__((ext_vector_type(4)));

__global__ __launch_bounds__(NT, 4)
void iir_conv2d_kernel(const float4* __restrict__ x4,
                       const float* __restrict__ w1,   // (C,1,5)
                       const float* __restrict__ w2,   // (C,3)
                       float4* __restrict__ y4)
{
    __shared__ float4 tile[TROWS * ROWP4];   // 18432 B; x then y in place
    __shared__ float  Htab[32][3];           // homogeneous responses
    __shared__ float  TP[3][3][3];           // T^2, T^4, T^8

    const int tid  = threadIdx.x;
    const int lane = tid & 63;
    const int row0 = blockIdx.x * TROWS;     // 8 | 512 -> channel uniform per block
    const int c    = (row0 >> 9) & 63;

    // ---- issue coalesced global loads first (stay in flight under setup) ----
    const float4* __restrict__ xb = x4 + (size_t)row0 * F4ROW;
    float4 st[8];
    #pragma unroll
    for (int it = 0; it < 8; ++it) st[it] = xb[it * NT + tid];

    const float v0 = w2[c*3+0], v1 = w2[c*3+1], v2 = w2[c*3+2];

    // ---- Htab + T powers (thread 0; hidden under load latency) ----
    if (tid == 0) {
        float h3[3] = {1.f, 0.f, 0.f};
        float h2[3] = {0.f, 1.f, 0.f};
        float h1[3] = {0.f, 0.f, 1.f};
        for (int k = 0; k < 32; ++k) {
            #pragma unroll
            for (int j = 0; j < 3; ++j) {
                const float n = -(v0*h3[j] + v1*h2[j] + v2*h1[j]);
                Htab[k][j] = n;
                h3[j] = h2[j]; h2[j] = h1[j]; h1[j] = n;
            }
        }
        float T1[3][3], T2[3][3], T4[3][3];
        #pragma unroll
        for (int i = 0; i < 3; ++i)
            #pragma unroll
            for (int j = 0; j < 3; ++j) T1[i][j] = Htab[29+i][j];
        #pragma unroll
        for (int i = 0; i < 3; ++i)
            #pragma unroll
            for (int j = 0; j < 3; ++j) {
                float acc = 0.f;
                #pragma unroll
                for (int k = 0; k < 3; ++k) acc += T1[i][k]*T1[k][j];
                T2[i][j] = acc; TP[0][i][j] = acc;
            }
        #pragma unroll
        for (int i = 0; i < 3; ++i)
            #pragma unroll
            for (int j = 0; j < 3; ++j) {
                float acc = 0.f;
                #pragma unroll
                for (int k = 0; k < 3; ++k) acc += T2[i][k]*T2[k][j];
                T4[i][j] = acc; TP[1][i][j] = acc;
            }
        #pragma unroll
        for (int i = 0; i < 3; ++i)
            #pragma unroll
            for (int j = 0; j < 3; ++j) {
                float acc = 0.f;
                #pragma unroll
                for (int k = 0; k < 3; ++k) acc += T4[i][k]*T4[k][j];
                TP[2][i][j] = acc;
            }
    }

    // ---- stage x into LDS ----
    #pragma unroll
    for (int it = 0; it < 8; ++it) {
        const int idx = it * NT + tid;
        const int r = idx >> 7, g = idx & 127;
        tile[r * ROWP4 + (g >> 3) * SEGP4 + (g & 7)] = st[it];
    }
    __syncthreads();

    // ---- phase 1: particular solution per segment ----
    const int r = tid >> 4;        // row in tile
    const int s = tid & 15;        // segment
    const float a0 = w1[c*5+0], a1 = w1[c*5+1], a2 = w1[c*5+2],
                a3 = w1[c*5+3], a4 = w1[c*5+4];

    float xfl[40];                 // cols j0-4 .. j0+35
    #pragma unroll
    for (int k = 0; k < 10; ++k) {
        const int g = s * 8 + k - 1;
        const bool valid = (g >= 0) && (g < F4ROW);
        const int gg = valid ? g : 0;
        float4 v = tile[r * ROWP4 + (gg >> 3) * SEGP4 + (gg & 7)];
        if (!valid) { v.x = 0.f; v.y = 0.f; v.z = 0.f; v.w = 0.f; }
        xfl[4*k+0] = v.x; xfl[4*k+1] = v.y; xfl[4*k+2] = v.z; xfl[4*k+3] = v.w;
    }
    float y[32];
    {
        float ym3 = 0.f, ym2 = 0.f, ym1 = 0.f;
        #pragma unroll
        for (int k = 0; k < 32; ++k) {
            const float f = a0*xfl[k+2] + a1*xfl[k+3] + a2*xfl[k+4]
                          + a3*xfl[k+5] + a4*xfl[k+6];
            const float t = v0*ym3 + v1*ym2;      // off the serial chain
            const float yy = (f - t) - v2*ym1;
            y[k] = yy;
            ym3 = ym2; ym2 = ym1; ym1 = yy;
        }
    }

    // ---- affine scan over segments (in-wave, shuffles only) ----
    float b0 = y[29], b1 = y[30], b2 = y[31];
    #pragma unroll
    for (int rd = 0; rd < 4; ++rd) {
        const int d = 1 << rd;
        float t00, t01, t02, t10, t11, t12, t20, t21, t22;
        if (rd == 0) {
            t00 = Htab[29][0]; t01 = Htab[29][1]; t02 = Htab[29][2];
            t10 = Htab[30][0]; t11 = Htab[30][1]; t12 = Htab[30][2];
            t20 = Htab[31][0]; t21 = Htab[31][1]; t22 = Htab[31][2];
        } else {
            t00 = TP[rd-1][0][0]; t01 = TP[rd-1][0][1]; t02 = TP[rd-1][0][2];
            t10 = TP[rd-1][1][0]; t11 = TP[rd-1][1][1]; t12 = TP[rd-1][1][2];
            t20 = TP[rd-1][2][0]; t21 = TP[rd-1][2][1]; t22 = TP[rd-1][2][2];
        }
        const int src = (s >= d) ? (lane - d) : lane;
        const float g0 = __shfl(b0, src, 64);
        const float g1 = __shfl(b1, src, 64);
        const float g2 = __shfl(b2, src, 64);
        if (s >= d) {
            b0 += t00*g0 + t01*g1 + t02*g2;
            b1 += t10*g0 + t11*g1 + t12*g2;
            b2 += t20*g0 + t21*g1 + t22*g2;
        }
    }
    // entering state for this segment = inclusive scan of previous segment
    {
        const int src = (s >= 1) ? (lane - 1) : lane;
        float s0 = __shfl(b0, src, 64);
        float s1 = __shfl(b1, src, 64);
        float s2 = __shfl(b2, src, 64);
        if (s == 0) { s0 = 0.f; s1 = 0.f; s2 = 0.f; }
        #pragma unroll
        for (int k = 0; k < 32; ++k)
            y[k] += Htab[k][0]*s0 + Htab[k][1]*s1 + Htab[k][2]*s2;
    }
    __syncthreads();   // all tile reads (phase 1) complete before overwrite

    // ---- write y into tile (in place) ----
    #pragma unroll
    for (int u = 0; u < 8; ++u) {
        float4 o;
        o.x = y[4*u+0]; o.y = y[4*u+1]; o.z = y[4*u+2]; o.w = y[4*u+3];
        tile[r * ROWP4 + s * SEGP4 + u] = o;
    }
    __syncthreads();

    // ---- drain: NON-TEMPORAL stores (native vec type), 1KB/wave-instr ----
    floatx4* __restrict__ yb4 = reinterpret_cast<floatx4*>(y4 + (size_t)row0 * F4ROW);
    const floatx4* __restrict__ tfx = reinterpret_cast<const floatx4*>(tile);
    #pragma unroll
    for (int it = 0; it < 8; ++it) {
        const int idx = it * NT + tid;      // float4 index 0..1023, contiguous
        const int rr  = idx >> 7;           // 128 float4 per row
        const int g   = idx & 127;
        const floatx4 v = tfx[rr * ROWP4 + (g >> 3) * SEGP4 + (g & 7)];
        __builtin_nontemporal_store(v, &yb4[idx]);
    }
}

extern "C" void kernel_launch(void* const* d_in, const int* in_sizes, int n_in,
                              void* d_out, int out_size, void* d_ws, size_t ws_size,
                              hipStream_t stream) {
    const float4* x4 = (const float4*)d_in[0];
    const float*  w1 = (const float*)d_in[1];
    const float*  w2 = (const float*)d_in[2];
    float4* y4 = (float4*)d_out;

    const int nrows  = out_size / Wd;        // 131072
    const int blocks = nrows / TROWS;        // 16384
    iir_conv2d_kernel<<<blocks, NT, 0, stream>>>(x4, w1, w2, y4);
}

// Round 9
// 121.626 us; speedup vs baseline: 1.3524x; 1.2532x over previous
//
#include <hip/hip_runtime.h>

// x: (B=4, C=64, H=512, W=512) fp32 -> 131072 independent rows of 512 cols.
// FIR: f[j] = sum_k a[k]*x[j-2+k] (SAME zero-pad), then IIR:
//   y[j] = f[j] - (v0*y[j-3] + v1*y[j-2] + v2*y[j-1]), zero initial state.
//
// R9: register-resident, near-barrier-free formulation.
//   thread = (row, 16-col segment); 8 rows x 32 segs = 256 threads/block.
//   loads : 6 direct float4 per thread (window cols 16s-4 .. 16s+19)
//   phase1: particular solution y_p over 16 cols (zero entry state)
//   scan  : Hillis-Steele affine scan over 32 segments in each 32-lane group
//           (5 shuffle rounds; T^d maintained per-thread by 3x3 squaring)
//   fixup : y[k] += H[.][k] . s_enter   (H = 192B LDS, broadcast reads)
//   stores: 4 contiguous float4 per thread, straight from registers.
// One __syncthreads total; LDS = 192 B; occupancy VGPR-capped (target 6 w/SIMD).

constexpr int Wd    = 512;
constexpr int TROWS = 8;
constexpr int NT    = 256;
constexpr int F4ROW = Wd / 4;   // 128

__global__ __launch_bounds__(NT, 6)
void iir_conv2d_kernel(const float4* __restrict__ x4,
                       const float* __restrict__ w1,   // (C,1,5)
                       const float* __restrict__ w2,   // (C,3)
                       float4* __restrict__ y4)
{
    __shared__ float H[3][16];   // H[j][k]: y[k] response to unit entry state e_j

    const int tid  = threadIdx.x;
    const int lane = tid & 63;
    const int r    = tid >> 5;          // row within block (0..7)
    const int s    = tid & 31;          // 16-col segment (0..31)
    const int row0 = blockIdx.x * TROWS;   // 8 | 512 -> channel uniform per block
    const int row  = row0 + r;
    const int c    = (row0 >> 9) & 63;

    // taps (wave-uniform, L1 broadcast)
    const float a0 = w1[c*5+0], a1 = w1[c*5+1], a2 = w1[c*5+2],
                a3 = w1[c*5+3], a4 = w1[c*5+4];
    const float v0 = w2[c*3+0], v1 = w2[c*3+1], v2 = w2[c*3+2];

    // ---- issue 6 direct float4 loads: cols 16s-4 .. 16s+19 of this row ----
    const float4* __restrict__ xr = x4 + (size_t)row * F4ROW;
    float4 xv[6];
    #pragma unroll
    for (int k = 0; k < 6; ++k) {
        const int g = 4*s - 1 + k;
        float4 t = {0.f, 0.f, 0.f, 0.f};
        if (g >= 0 && g < F4ROW) t = xr[g];   // OOB only at s=0 / s=31 edges
        xv[k] = t;
    }

    // ---- H table: 3 threads compute the 3 columns (16-step recursions) ----
    if (tid < 3) {
        const int j = tid;
        float h3 = (j==0) ? 1.f : 0.f;
        float h2 = (j==1) ? 1.f : 0.f;
        float h1 = (j==2) ? 1.f : 0.f;
        #pragma unroll
        for (int k = 0; k < 16; ++k) {
            const float n = -(v0*h3 + v1*h2 + v2*h1);
            H[j][k] = n;
            h3 = h2; h2 = h1; h1 = n;
        }
    }

    // ---- unpack window ----
    float xw[24];
    #pragma unroll
    for (int k = 0; k < 6; ++k) {
        xw[4*k+0] = xv[k].x; xw[4*k+1] = xv[k].y;
        xw[4*k+2] = xv[k].z; xw[4*k+3] = xv[k].w;
    }

    // ---- phase 1: particular solution (zero entry state) ----
    float y[16];
    {
        float ym3 = 0.f, ym2 = 0.f, ym1 = 0.f;
        #pragma unroll
        for (int k = 0; k < 16; ++k) {
            // col 16s+k needs x[col-2..col+2] = xw[k+2..k+6]
            const float f = a0*xw[k+2] + a1*xw[k+3] + a2*xw[k+4]
                          + a3*xw[k+5] + a4*xw[k+6];
            const float t = v0*ym3 + v1*ym2;      // off the serial chain
            const float yy = (f - t) - v2*ym1;
            y[k] = yy;
            ym3 = ym2; ym2 = ym1; ym1 = yy;
        }
    }

    __syncthreads();   // H ready (the only barrier)

    // ---- T = 16-step state transform: T[i][j] = H[j][13+i] ----
    float M[3][3];
    #pragma unroll
    for (int i = 0; i < 3; ++i)
        #pragma unroll
        for (int j = 0; j < 3; ++j) M[i][j] = H[j][13+i];

    // ---- affine scan over 32 segments (within each 32-lane group) ----
    float b0 = y[13], b1 = y[14], b2 = y[15];
    #pragma unroll
    for (int rd = 0; rd < 5; ++rd) {
        const int d = 1 << rd;
        const int src = (s >= d) ? (lane - d) : lane;
        const float g0 = __shfl(b0, src, 64);
        const float g1 = __shfl(b1, src, 64);
        const float g2 = __shfl(b2, src, 64);
        if (s >= d) {
            b0 += M[0][0]*g0 + M[0][1]*g1 + M[0][2]*g2;
            b1 += M[1][0]*g0 + M[1][1]*g1 + M[1][2]*g2;
            b2 += M[2][0]*g0 + M[2][1]*g1 + M[2][2]*g2;
        }
        if (rd < 4) {   // M <- M*M for the next round
            float N[3][3];
            #pragma unroll
            for (int i = 0; i < 3; ++i)
                #pragma unroll
                for (int j = 0; j < 3; ++j)
                    N[i][j] = M[i][0]*M[0][j] + M[i][1]*M[1][j] + M[i][2]*M[2][j];
            #pragma unroll
            for (int i = 0; i < 3; ++i)
                #pragma unroll
                for (int j = 0; j < 3; ++j) M[i][j] = N[i][j];
        }
    }

    // ---- entering state = inclusive scan of previous segment; fixup ----
    {
        const int src = (s >= 1) ? (lane - 1) : lane;
        float s0 = __shfl(b0, src, 64);
        float s1 = __shfl(b1, src, 64);
        float s2 = __shfl(b2, src, 64);
        if (s == 0) { s0 = 0.f; s1 = 0.f; s2 = 0.f; }
        #pragma unroll
        for (int k = 0; k < 16; ++k)
            y[k] += H[0][k]*s0 + H[1][k]*s1 + H[2][k]*s2;
    }

    // ---- store: 4 contiguous float4 per thread, straight from registers ----
    float4* __restrict__ yr = y4 + (size_t)row * F4ROW;
    #pragma unroll
    for (int u = 0; u < 4; ++u) {
        float4 o;
        o.x = y[4*u+0]; o.y = y[4*u+1]; o.z = y[4*u+2]; o.w = y[4*u+3];
        yr[4*s + u] = o;
    }
}

extern "C" void kernel_launch(void* const* d_in, const int* in_sizes, int n_in,
                              void* d_out, int out_size, void* d_ws, size_t ws_size,
                              hipStream_t stream) {
    const float4* x4 = (const float4*)d_in[0];
    const float*  w1 = (const float*)d_in[1];
    const float*  w2 = (const float*)d_in[2];
    float4* y4 = (float4*)d_out;

    const int nrows  = out_size / Wd;        // 131072
    const int blocks = nrows / TROWS;        // 16384
    iir_conv2d_kernel<<<blocks, NT, 0, stream>>>(x4, w1, w2, y4);
}

// Round 11
// 104.045 us; speedup vs baseline: 1.5809x; 1.1690x over previous
//
#include <hip/hip_runtime.h>

// x: (B=4, C=64, H=512, W=512) fp32 -> 131072 independent rows of 512 cols.
// FIR: f[j] = sum_k a[k]*x[j-2+k] (SAME zero-pad), then IIR:
//   y[j] = f[j] - (v0*y[j-3] + v1*y[j-2] + v2*y[j-1]), zero initial state.
//
// R11 = R9 + ONE change: in-register store transpose (shuffles) so each
// wave store instruction writes contiguous full cache lines
// (lane i stores float4 32u+i of its row -> 2x512B segments per instr),
// instead of 64 lanes x 16B at 256B stride (partial-line scatter).
//
//   thread = (row, 16-col segment); 8 rows x 32 segs = 256 threads/block.
//   loads : 6 direct float4 per thread (window cols 16s-4 .. 16s+19)
//   phase1: particular solution y_p over 16 cols (zero entry state)
//   scan  : Hillis-Steele affine scan over 32 segments per 32-lane group
//   fixup : y[k] += H[.][k] . s_enter   (H = 192B LDS, broadcast reads)
//   stores: shuffle-transposed, 4 coalesced float4 per thread.

constexpr int Wd    = 512;
constexpr int TROWS = 8;
constexpr int NT    = 256;
constexpr int F4ROW = Wd / 4;   // 128

__global__ __launch_bounds__(NT, 6)
void iir_conv2d_kernel(const float4* __restrict__ x4,
                       const float* __restrict__ w1,   // (C,1,5)
                       const float* __restrict__ w2,   // (C,3)
                       float4* __restrict__ y4)
{
    __shared__ float H[3][16];   // H[j][k]: y[k] response to unit entry state e_j

    const int tid  = threadIdx.x;
    const int lane = tid & 63;
    const int r    = tid >> 5;          // row within block (0..7)
    const int s    = tid & 31;          // 16-col segment (0..31)
    const int row0 = blockIdx.x * TROWS;   // 8 | 512 -> channel uniform per block
    const int row  = row0 + r;
    const int c    = (row0 >> 9) & 63;

    // taps (wave-uniform, L1 broadcast)
    const float a0 = w1[c*5+0], a1 = w1[c*5+1], a2 = w1[c*5+2],
                a3 = w1[c*5+3], a4 = w1[c*5+4];
    const float v0 = w2[c*3+0], v1 = w2[c*3+1], v2 = w2[c*3+2];

    // ---- issue 6 direct float4 loads: cols 16s-4 .. 16s+19 of this row ----
    const float4* __restrict__ xr = x4 + (size_t)row * F4ROW;
    float4 xv[6];
    #pragma unroll
    for (int k = 0; k < 6; ++k) {
        const int g = 4*s - 1 + k;
        float4 t = {0.f, 0.f, 0.f, 0.f};
        if (g >= 0 && g < F4ROW) t = xr[g];   // OOB only at s=0 / s=31 edges
        xv[k] = t;
    }

    // ---- H table: 3 threads compute the 3 columns (16-step recursions) ----
    if (tid < 3) {
        const int j = tid;
        float h3 = (j==0) ? 1.f : 0.f;
        float h2 = (j==1) ? 1.f : 0.f;
        float h1 = (j==2) ? 1.f : 0.f;
        #pragma unroll
        for (int k = 0; k < 16; ++k) {
            const float n = -(v0*h3 + v1*h2 + v2*h1);
            H[j][k] = n;
            h3 = h2; h2 = h1; h1 = n;
        }
    }

    // ---- unpack window ----
    float xw[24];
    #pragma unroll
    for (int k = 0; k < 6; ++k) {
        xw[4*k+0] = xv[k].x; xw[4*k+1] = xv[k].y;
        xw[4*k+2] = xv[k].z; xw[4*k+3] = xv[k].w;
    }

    // ---- phase 1: particular solution (zero entry state) ----
    float y[16];
    {
        float ym3 = 0.f, ym2 = 0.f, ym1 = 0.f;
        #pragma unroll
        for (int k = 0; k < 16; ++k) {
            // col 16s+k needs x[col-2..col+2] = xw[k+2..k+6]
            const float f = a0*xw[k+2] + a1*xw[k+3] + a2*xw[k+4]
                          + a3*xw[k+5] + a4*xw[k+6];
            const float t = v0*ym3 + v1*ym2;      // off the serial chain
            const float yy = (f - t) - v2*ym1;
            y[k] = yy;
            ym3 = ym2; ym2 = ym1; ym1 = yy;
        }
    }

    __syncthreads();   // H ready (the only barrier)

    // ---- T = 16-step state transform: T[i][j] = H[j][13+i] ----
    float M[3][3];
    #pragma unroll
    for (int i = 0; i < 3; ++i)
        #pragma unroll
        for (int j = 0; j < 3; ++j) M[i][j] = H[j][13+i];

    // ---- affine scan over 32 segments (within each 32-lane group) ----
    float b0 = y[13], b1 = y[14], b2 = y[15];
    #pragma unroll
    for (int rd = 0; rd < 5; ++rd) {
        const int d = 1 << rd;
        const int src = (s >= d) ? (lane - d) : lane;
        const float g0 = __shfl(b0, src, 64);
        const float g1 = __shfl(b1, src, 64);
        const float g2 = __shfl(b2, src, 64);
        if (s >= d) {
            b0 += M[0][0]*g0 + M[0][1]*g1 + M[0][2]*g2;
            b1 += M[1][0]*g0 + M[1][1]*g1 + M[1][2]*g2;
            b2 += M[2][0]*g0 + M[2][1]*g1 + M[2][2]*g2;
        }
        if (rd < 4) {   // M <- M*M for the next round
            float N[3][3];
            #pragma unroll
            for (int i = 0; i < 3; ++i)
                #pragma unroll
                for (int j = 0; j < 3; ++j)
                    N[i][j] = M[i][0]*M[0][j] + M[i][1]*M[1][j] + M[i][2]*M[2][j];
            #pragma unroll
            for (int i = 0; i < 3; ++i)
                #pragma unroll
                for (int j = 0; j < 3; ++j) M[i][j] = N[i][j];
        }
    }

    // ---- entering state = inclusive scan of previous segment; fixup ----
    {
        const int src = (s >= 1) ? (lane - 1) : lane;
        float s0 = __shfl(b0, src, 64);
        float s1 = __shfl(b1, src, 64);
        float s2 = __shfl(b2, src, 64);
        if (s == 0) { s0 = 0.f; s1 = 0.f; s2 = 0.f; }
        #pragma unroll
        for (int k = 0; k < 16; ++k)
            y[k] += H[0][k]*s0 + H[1][k]*s1 + H[2][k]*s2;
    }

    // ---- store: shuffle-transpose then coalesced float4 stores ----
    // Instr u: lane i (i=lane&31) stores f4 idx 32u+i of its row
    //   -> floats 128u+4i+m, owned by src lane 8u+(i>>2), reg 4*(i&3)+m.
    // Sub-round over q=(i&3) keeps all register indices compile-time.
    float4* __restrict__ yrow = y4 + (size_t)row * F4ROW;
    #pragma unroll
    for (int u = 0; u < 4; ++u) {
        const int srcl = (lane & 32) | (8*u + ((lane & 31) >> 2));
        float out0, out1, out2, out3;
        #pragma unroll
        for (int q = 0; q < 4; ++q) {
            const float t0 = __shfl(y[4*q+0], srcl, 64);
            const float t1 = __shfl(y[4*q+1], srcl, 64);
            const float t2 = __shfl(y[4*q+2], srcl, 64);
            const float t3 = __shfl(y[4*q+3], srcl, 64);
            if ((lane & 3) == q) { out0 = t0; out1 = t1; out2 = t2; out3 = t3; }
        }
        float4 o; o.x = out0; o.y = out1; o.z = out2; o.w = out3;
        yrow[32*u + (lane & 31)] = o;
    }
}

extern "C" void kernel_launch(void* const* d_in, const int* in_sizes, int n_in,
                              void* d_out, int out_size, void* d_ws, size_t ws_size,
                              hipStream_t stream) {
    const float4* x4 = (const float4*)d_in[0];
    const float*  w1 = (const float*)d_in[1];
    const float*  w2 = (const float*)d_in[2];
    float4* y4 = (float4*)d_out;

    const int nrows  = out_size / Wd;        // 131072
    const int blocks = nrows / TROWS;        // 16384
    iir_conv2d_kernel<<<blocks, NT, 0, stream>>>(x4, w1, w2, y4);
}